// Round 2
// baseline (1005.053 us; speedup 1.0000x reference)
//
#include <hip/hip_runtime.h>
#include <hip/hip_bf16.h>

typedef __hip_bfloat16 bf16;

#define D 128
#define NLEV 5

// gate code -> t (enumerate index in CODES=[3,2,5,1,4]); index 0 unused
__constant__ int TMAP[6] = { -1, 3, 1, 0, 4, 2 };
// gate code -> func-aggregator index (FIDX={3:0,5:1,1:2,4:3}); codes 0,2 unused
__constant__ int FMAP[6] = { -1, 2, -1, 0, 3, 1 };

// dtype flag: 1 = float tensors stored as bf16, 0 = stored as float32
__device__ int g_flag;

__device__ __forceinline__ float sigm(float x) { return 1.0f / (1.0f + __expf(-x)); }

template <int ISB>
__device__ __forceinline__ float ld(const void* p, size_t i) {
    if (ISB) return __bfloat162float(((const bf16*)p)[i]);
    return ((const float*)p)[i];
}

// ---- dtype sniffer: read hs_init (~N(0,1)) as bf16 at even indices ----
// true bf16 buffer: ~100% of |x| in (1e-4, 64); f32 buffer read as bf16:
// even elements are float mantissa bits -> random exponents -> ~7% sane.
__global__ void detect_dtype(const void* hs_init) {
    int t = threadIdx.x;
    float x = __bfloat162float(((const bf16*)hs_init)[2 * t]);
    float ax = fabsf(x);
    bool sane = (x == 0.0f) || (ax > 1e-4f && ax < 64.0f);
    unsigned long long m = __ballot(sane);
    if (t == 0) g_flag = (__popcll(m) >= 32) ? 1 : 0;
}

// ---------------- init: hs = PI ? hs_init : 0 ; hf = 0 ----------------
__global__ void init_state(const void* __restrict__ hs_init,
                           const int* __restrict__ gate,
                           float* __restrict__ hs, float* __restrict__ hf) {
    int v = blockIdx.x;
    int j = threadIdx.x;
    float val = 0.0f;
    if (gate[v] == 0) {
        size_t idx = (size_t)v * D + j;
        val = g_flag ? ld<1>(hs_init, idx) : ld<0>(hs_init, idx);
    }
    hs[(size_t)v * D + j] = val;
    hf[(size_t)v * D + j] = 0.0f;
}

// ---------------- per-edge message MLPs + scatter-add ----------------
template <int ISB>
__device__ void edge_body(
    const float* __restrict__ hs, const float* __restrict__ hf,
    const void* __restrict__ Ws1, const void* __restrict__ bs1,
    const void* __restrict__ Ws2, const void* __restrict__ bs2,
    const void* __restrict__ Wf1, const void* __restrict__ bf1,
    const void* __restrict__ Wf2, const void* __restrict__ bf2,
    const void* __restrict__ Wnf1, const void* __restrict__ bnf1,
    const void* __restrict__ Wnf2, const void* __restrict__ bnf2,
    const int* __restrict__ srcA, const int* __restrict__ dstA,
    const int* __restrict__ gate, const int* __restrict__ lev,
    float* __restrict__ agg_s, float* __restrict__ agg_f,
    int E, int level) {
    int e = blockIdx.x;
    if (e >= E) return;
    int d = dstA[e];
    if (lev[d] != level) return;
    int s = srcA[e];
    int c = gate[d];      // 1..5, uniform across block
    int t = TMAP[c];

    __shared__ float x[2 * D];
    __shared__ float hid[D];
    int j = threadIdx.x;

    // ---- structural message: relu(hs[s] @ Ws1[t]) @ Ws2[t] ----
    x[j] = hs[(size_t)s * D + j];
    __syncthreads();
    {
        size_t W1 = (size_t)t * D * D;
        float acc = ld<ISB>(bs1, t * D + j);
#pragma unroll 8
        for (int i = 0; i < D; ++i) acc += x[i] * ld<ISB>(Ws1, W1 + i * D + j);
        hid[j] = fmaxf(acc, 0.0f);
    }
    __syncthreads();
    {
        size_t W2 = (size_t)t * D * D;
        float acc = ld<ISB>(bs2, t * D + j);
#pragma unroll 8
        for (int i = 0; i < D; ++i) acc += hid[i] * ld<ISB>(Ws2, W2 + i * D + j);
        atomicAdd(&agg_s[(size_t)d * D + j], acc);
    }
    __syncthreads();

    // ---- functional message ----
    if (c == 2) {  // NOT: relu(hf[s] @ Wnf1) @ Wnf2
        x[j] = hf[(size_t)s * D + j];
        __syncthreads();
        float acc = ld<ISB>(bnf1, j);
#pragma unroll 8
        for (int i = 0; i < D; ++i) acc += x[i] * ld<ISB>(Wnf1, i * D + j);
        hid[j] = fmaxf(acc, 0.0f);
        __syncthreads();
        acc = ld<ISB>(bnf2, j);
#pragma unroll 8
        for (int i = 0; i < D; ++i) acc += hid[i] * ld<ISB>(Wnf2, i * D + j);
        atomicAdd(&agg_f[(size_t)d * D + j], acc);
    } else {       // AND/XOR/MAJ/OR: relu([hs,hf][s] @ Wf1[fi]) @ Wf2[fi]
        int fi = FMAP[c];
        x[j] = hs[(size_t)s * D + j];
        x[D + j] = hf[(size_t)s * D + j];
        __syncthreads();
        float acc = ld<ISB>(bf1, fi * D + j);
        size_t F1 = (size_t)fi * 2 * D * D;
#pragma unroll 8
        for (int i = 0; i < 2 * D; ++i) acc += x[i] * ld<ISB>(Wf1, F1 + i * D + j);
        hid[j] = fmaxf(acc, 0.0f);
        __syncthreads();
        acc = ld<ISB>(bf2, fi * D + j);
        size_t F2 = (size_t)fi * D * D;
#pragma unroll 8
        for (int i = 0; i < D; ++i) acc += hid[i] * ld<ISB>(Wf2, F2 + i * D + j);
        atomicAdd(&agg_f[(size_t)d * D + j], acc);
    }
}

__global__ __launch_bounds__(D) void edge_msg(
    const float* hs, const float* hf,
    const void* Ws1, const void* bs1, const void* Ws2, const void* bs2,
    const void* Wf1, const void* bf1, const void* Wf2, const void* bf2,
    const void* Wnf1, const void* bnf1, const void* Wnf2, const void* bnf2,
    const int* srcA, const int* dstA, const int* gate, const int* lev,
    float* agg_s, float* agg_f, int E, int level) {
    if (g_flag)
        edge_body<1>(hs, hf, Ws1, bs1, Ws2, bs2, Wf1, bf1, Wf2, bf2,
                     Wnf1, bnf1, Wnf2, bnf2, srcA, dstA, gate, lev,
                     agg_s, agg_f, E, level);
    else
        edge_body<0>(hs, hf, Ws1, bs1, Ws2, bs2, Wf1, bf1, Wf2, bf2,
                     Wnf1, bnf1, Wnf2, bnf2, srcA, dstA, gate, lev,
                     agg_s, agg_f, E, level);
}

// ---------------- per-node simplified GRU (h == 0 at update time) ----------------
template <int ISB>
__device__ void gru_half(
    float* __restrict__ h, const float* __restrict__ agg,
    const void* __restrict__ wihp, const void* __restrict__ bihp,
    const void* __restrict__ bhhp,
    int v, int t, int j, float* a) {
    a[j] = agg[(size_t)v * D + j];
    __syncthreads();
    size_t wih = (size_t)t * D * 3 * D;
    float gr = ld<ISB>(bihp, t * 3 * D + j);
    float gz = ld<ISB>(bihp, t * 3 * D + D + j);
    float gn = ld<ISB>(bihp, t * 3 * D + 2 * D + j);
#pragma unroll 4
    for (int i = 0; i < D; ++i) {
        float xi = a[i];
        size_t row = wih + (size_t)i * 3 * D;
        gr += xi * ld<ISB>(wihp, row + j);
        gz += xi * ld<ISB>(wihp, row + D + j);
        gn += xi * ld<ISB>(wihp, row + 2 * D + j);
    }
    float hr = ld<ISB>(bhhp, t * 3 * D + j);
    float hz = ld<ISB>(bhhp, t * 3 * D + D + j);
    float hn = ld<ISB>(bhhp, t * 3 * D + 2 * D + j);
    float r = sigm(gr + hr);
    float z = sigm(gz + hz);
    float n = tanhf(gn + r * hn);
    h[(size_t)v * D + j] = (1.0f - z) * n;
    __syncthreads();
}

template <int ISB>
__device__ void node_body(
    float* hs, float* hf, const float* agg_s, const float* agg_f,
    const void* Gs_wih, const void* Gs_bih, const void* Gs_bhh,
    const void* Gf_wih, const void* Gf_bih, const void* Gf_bhh,
    const int* gate, const int* lev, int N, int level) {
    int v = blockIdx.x;
    if (v >= N) return;
    if (lev[v] != level) return;
    int t = TMAP[gate[v]];
    int j = threadIdx.x;
    __shared__ float a[D];
    gru_half<ISB>(hs, agg_s, Gs_wih, Gs_bih, Gs_bhh, v, t, j, a);
    gru_half<ISB>(hf, agg_f, Gf_wih, Gf_bih, Gf_bhh, v, t, j, a);
}

__global__ __launch_bounds__(D) void node_gru(
    float* hs, float* hf, const float* agg_s, const float* agg_f,
    const void* Gs_wih, const void* Gs_bih, const void* Gs_bhh,
    const void* Gf_wih, const void* Gf_bih, const void* Gf_bhh,
    const int* gate, const int* lev, int N, int level) {
    if (g_flag)
        node_body<1>(hs, hf, agg_s, agg_f, Gs_wih, Gs_bih, Gs_bhh,
                     Gf_wih, Gf_bih, Gf_bhh, gate, lev, N, level);
    else
        node_body<0>(hs, hf, agg_s, agg_f, Gs_wih, Gs_bih, Gs_bhh,
                     Gf_wih, Gf_bih, Gf_bhh, gate, lev, N, level);
}

// ---------------- writeout: d_out = [hs, hf] in detected dtype ----------------
__global__ void writeout(const float* __restrict__ hs, const float* __restrict__ hf,
                         void* __restrict__ out, int ND) {
    int i = blockIdx.x * blockDim.x + threadIdx.x;
    if (i >= ND) return;
    if (g_flag) {
        ((bf16*)out)[i] = __float2bfloat16(hs[i]);
        ((bf16*)out)[ND + i] = __float2bfloat16(hf[i]);
    } else {
        ((float*)out)[i] = hs[i];
        ((float*)out)[ND + i] = hf[i];
    }
}

extern "C" void kernel_launch(void* const* d_in, const int* in_sizes, int n_in,
                              void* d_out, int out_size, void* d_ws, size_t ws_size,
                              hipStream_t stream) {
    const void* hs_init = d_in[0];
    const void* Ws1 = d_in[1];
    const void* bs1 = d_in[2];
    const void* Ws2 = d_in[3];
    const void* bs2 = d_in[4];
    const void* Wf1 = d_in[5];
    const void* bf1 = d_in[6];
    const void* Wf2 = d_in[7];
    const void* bf2 = d_in[8];
    const void* Wnf1 = d_in[9];
    const void* bnf1 = d_in[10];
    const void* Wnf2 = d_in[11];
    const void* bnf2 = d_in[12];
    const void* Gs_wih = d_in[13];
    // d_in[14] = Gs_whh (unused: h==0 at GRU time)
    const void* Gs_bih = d_in[15];
    const void* Gs_bhh = d_in[16];
    const void* Gf_wih = d_in[17];
    // d_in[18] = Gf_whh (unused)
    const void* Gf_bih = d_in[19];
    const void* Gf_bhh = d_in[20];
    const int* edge_index = (const int*)d_in[21];
    const int* gate = (const int*)d_in[22];
    const int* lev = (const int*)d_in[23];

    int E = in_sizes[21] / 2;
    int N = in_sizes[22];
    int ND = N * D;

    float* hs = (float*)d_ws;
    float* hf = hs + ND;
    float* agg_s = hf + ND;
    float* agg_f = agg_s + ND;

    const int* srcA = edge_index;
    const int* dstA = edge_index + E;

    detect_dtype<<<1, 64, 0, stream>>>(hs_init);
    // each node aggregates only in its own level; zero once up front
    hipMemsetAsync(agg_s, 0, (size_t)2 * ND * sizeof(float), stream);
    init_state<<<N, D, 0, stream>>>(hs_init, gate, hs, hf);

    for (int level = 1; level < NLEV; ++level) {
        edge_msg<<<E, D, 0, stream>>>(hs, hf, Ws1, bs1, Ws2, bs2,
                                      Wf1, bf1, Wf2, bf2,
                                      Wnf1, bnf1, Wnf2, bnf2,
                                      srcA, dstA, gate, lev,
                                      agg_s, agg_f, E, level);
        node_gru<<<N, D, 0, stream>>>(hs, hf, agg_s, agg_f,
                                      Gs_wih, Gs_bih, Gs_bhh,
                                      Gf_wih, Gf_bih, Gf_bhh,
                                      gate, lev, N, level);
    }

    writeout<<<(ND + 255) / 256, 256, 0, stream>>>(hs, hf, d_out, ND);
}